// Round 5
// baseline (162.336 us; speedup 1.0000x reference)
//
#include <hip/hip_runtime.h>
#include <math.h>

#define IMG_W 512
#define IMG_H 512
#define NIMG 16
#define HWSZ (IMG_W * IMG_H)          // 262144
#define CHWSZ (3 * HWSZ)              // 786432
#define NORM (1.0 / 4194304.0)        // 1 / (N*H*W)
#define NBLK_V 1536                   // 48 nc x 16 segs x 2 halves

__device__ __forceinline__ float f_lab(float t) {
    float c = exp2f(log2f(t) * (1.0f / 3.0f));   // cbrt; small-t branch selected away
    return (t > 0.008856f) ? c : fmaf(7.787f, t, 0.13793103448275862f);
}

__device__ __forceinline__ void rgb_to_luv(float r, float g, float b,
                                           float& l, float& u, float& v) {
    float x = 0.4124564f * r + 0.3575761f * g + 0.1804375f * b;
    float y = 0.2126729f * r + 0.7151522f * g + 0.0721750f * b;
    float z = 0.0193339f * r + 0.1191920f * g + 0.9503041f * b;
    x *= (1.0f / 0.95047f);
    z *= (1.0f / 1.08883f);
    float fx = f_lab(x), fy = f_lab(y), fz = f_lab(z);
    l = 116.0f * fy - 16.0f;
    u = 13.0f * l * (fx - fy);
    v = 13.0f * l * (fy - fz);
}

__device__ __forceinline__ unsigned short f2bf(float x) {   // RNE f32->bf16
    unsigned int u = __float_as_uint(x);
    u += 0x7fff + ((u >> 16) & 1);
    return (unsigned short)(u >> 16);
}

// 15-tap horizontal sliding window across a wave-owned 512-px row (8 px/lane);
// halo via lane shuffles, zero padding at row ends. (validated R3)
__device__ __forceinline__ void hslide(const float d[8], float o[8], int lane) {
    float L[7], R[7];
    #pragma unroll
    for (int j = 0; j < 7; ++j) {
        float l = __shfl_up(d[j + 1], 1, 64);
        L[j] = (lane == 0) ? 0.0f : l;
        float r = __shfl_down(d[j], 1, 64);
        R[j] = (lane == 63) ? 0.0f : r;
    }
    float s = 0.0f;
    #pragma unroll
    for (int j = 0; j < 7; ++j) s += L[j];
    #pragma unroll
    for (int j = 0; j < 8; ++j) s += d[j];
    o[0] = s;
    #pragma unroll
    for (int k = 1; k < 8; ++k) o[k] = o[k - 1] + R[k - 1] - L[k - 1];
}

__device__ __forceinline__ uint4 pack8(const float o[8]) {
    uint4 p;
    p.x = (unsigned)f2bf(o[0]) | ((unsigned)f2bf(o[1]) << 16);
    p.y = (unsigned)f2bf(o[2]) | ((unsigned)f2bf(o[3]) << 16);
    p.z = (unsigned)f2bf(o[4]) | ((unsigned)f2bf(o[5]) << 16);
    p.w = (unsigned)f2bf(o[6]) | ((unsigned)f2bf(o[7]) << 16);
    return p;
}

// Block = 4 waves = 4 rows; wave owns a full 512-px row (8 px/lane).
// No LDS, no barrier. Also zeroes the acc/cnt cells used by vpass4 (block 0).
__global__ __launch_bounds__(256) void luv_hpass3(
        const float* __restrict__ inp, const float* __restrict__ tgt,
        unsigned short* __restrict__ tmp, float* __restrict__ acc,
        unsigned int* __restrict__ cnt) {
    int blk = blockIdx.x;
    if (blk == 0 && threadIdx.x == 0) { acc[0] = 0.0f; cnt[0] = 0u; }
    int n = blk >> 7;                            // 128 row-quads per image
    int lane = threadIdx.x & 63;
    int h = ((blk & 127) << 2) | (threadIdx.x >> 6);
    int w0 = lane << 3;
    size_t base = (size_t)n * CHWSZ + (size_t)h * IMG_W + w0;

    float dl[8], du[8], dv[8];
    {
        float R[8], G[8], B[8];
        *(float4*)&R[0] = *(const float4*)(inp + base);
        *(float4*)&R[4] = *(const float4*)(inp + base + 4);
        *(float4*)&G[0] = *(const float4*)(inp + base + HWSZ);
        *(float4*)&G[4] = *(const float4*)(inp + base + HWSZ + 4);
        *(float4*)&B[0] = *(const float4*)(inp + base + 2 * HWSZ);
        *(float4*)&B[4] = *(const float4*)(inp + base + 2 * HWSZ + 4);
        #pragma unroll
        for (int j = 0; j < 8; ++j)
            rgb_to_luv(R[j], G[j], B[j], dl[j], du[j], dv[j]);
        *(float4*)&R[0] = *(const float4*)(tgt + base);
        *(float4*)&R[4] = *(const float4*)(tgt + base + 4);
        *(float4*)&G[0] = *(const float4*)(tgt + base + HWSZ);
        *(float4*)&G[4] = *(const float4*)(tgt + base + HWSZ + 4);
        *(float4*)&B[0] = *(const float4*)(tgt + base + 2 * HWSZ);
        *(float4*)&B[4] = *(const float4*)(tgt + base + 2 * HWSZ + 4);
        #pragma unroll
        for (int j = 0; j < 8; ++j) {
            float l2, u2, v2;
            rgb_to_luv(R[j], G[j], B[j], l2, u2, v2);
            dl[j] -= l2; du[j] -= u2; dv[j] -= v2;
        }
    }

    float o[8];
    hslide(dl, o, lane);
    *reinterpret_cast<uint4*>(tmp + base) = pack8(o);
    hslide(du, o, lane);
    *reinterpret_cast<uint4*>(tmp + base + HWSZ) = pack8(o);
    hslide(dv, o, lane);
    *reinterpret_cast<uint4*>(tmp + base + 2 * HWSZ) = pack8(o);
}

__device__ __forceinline__ void unpack4(uint2 v, float f[4]) {
    f[0] = __uint_as_float(v.x << 16);
    f[1] = __uint_as_float(v.x & 0xffff0000u);
    f[2] = __uint_as_float(v.y << 16);
    f[3] = __uint_as_float(v.y & 0xffff0000u);
}

template <bool GLO>
__device__ __forceinline__ void vprime4(const unsigned short* __restrict__ col,
                                        int h0, float W[4]) {
    #pragma unroll
    for (int j = 0; j < 15; ++j) {
        int h = h0 - 7 + j;
        if (GLO && h < 0) continue;              // resolved at unroll time
        uint2 v = *(const uint2*)(col + (size_t)h * IMG_W);
        float a[4];
        unpack4(v, a);
        #pragma unroll
        for (int c = 0; c < 4; ++c) W[c] += a[c];
    }
}

// 8 output rows: batch 16 independent uint2 loads, then register updates.
template <bool GLO, bool GHI>
__device__ __forceinline__ void vchunk8_4(const unsigned short* __restrict__ col,
                                          int hb, float W[4], float& acc) {
    const uint2 z = make_uint2(0u, 0u);
    uint2 va[8], vs[8];
    #pragma unroll
    for (int j = 0; j < 8; ++j) {
        int ha = hb + j + 8, hs = hb + j - 7;
        va[j] = (GHI && ha >= IMG_H) ? z : *(const uint2*)(col + (size_t)ha * IMG_W);
        vs[j] = (GLO && hs < 0)      ? z : *(const uint2*)(col + (size_t)hs * IMG_W);
    }
    #pragma unroll
    for (int j = 0; j < 8; ++j) {
        float a[4], s[4];
        unpack4(va[j], a);
        unpack4(vs[j], s);
        #pragma unroll
        for (int c = 0; c < 4; ++c) {
            acc += W[c] * W[c];                  // square window centered at hb+j
            W[c] += a[c] - s[c];                 // advance to hb+j+1
        }
    }
}

// One wave per block; thread owns 4 bf16 columns (uint2 per row).
// Grid: 48 nc x 16 segs of 32 output rows x 2 column halves.
// Last finishing block writes the final scalar to out (ticket pattern).
__global__ __launch_bounds__(64) void vpass4(
        const unsigned short* __restrict__ tmp, float* __restrict__ acc,
        unsigned int* __restrict__ cnt, float* __restrict__ out) {
    int blk = blockIdx.x;
    int half = blk & 1;
    int seg = (blk >> 1) & 15;
    int nc = blk >> 5;                           // 0..47
    int t = (int)threadIdx.x;
    const unsigned short* col = tmp + (size_t)nc * HWSZ + (half << 8) + (t << 2);
    int h0 = seg << 5;

    float W[4] = {0.f, 0.f, 0.f, 0.f};
    float a = 0.0f;

    if (seg == 0) {
        vprime4<true>(col, h0, W);
        vchunk8_4<true,  false>(col, h0,      W, a);   // rows 0..7 (hs<0 guarded)
        vchunk8_4<false, false>(col, h0 + 8,  W, a);
        vchunk8_4<false, false>(col, h0 + 16, W, a);
        vchunk8_4<false, false>(col, h0 + 24, W, a);
    } else if (seg == 15) {
        vprime4<false>(col, h0, W);
        vchunk8_4<false, false>(col, h0,      W, a);
        vchunk8_4<false, false>(col, h0 + 8,  W, a);
        vchunk8_4<false, false>(col, h0 + 16, W, a);   // ha max 511
        vchunk8_4<false, true >(col, h0 + 24, W, a);   // ha 512..519 guarded
    } else {
        vprime4<false>(col, h0, W);
        vchunk8_4<false, false>(col, h0,      W, a);
        vchunk8_4<false, false>(col, h0 + 8,  W, a);
        vchunk8_4<false, false>(col, h0 + 16, W, a);
        vchunk8_4<false, false>(col, h0 + 24, W, a);
    }

    #pragma unroll
    for (int off = 32; off > 0; off >>= 1)
        a += __shfl_down(a, off, 64);

    if (t == 0) {
        atomicAdd(acc, a);
        __threadfence();
        unsigned int ticket = atomicAdd(cnt, 1u);
        if (ticket == NBLK_V - 1) {
            __threadfence();
            float s = atomicAdd(acc, 0.0f);      // all adds complete & visible
            out[0] = (float)((double)s * NORM);
        }
    }
}

extern "C" void kernel_launch(void* const* d_in, const int* in_sizes, int n_in,
                              void* d_out, int out_size, void* d_ws, size_t ws_size,
                              hipStream_t stream) {
    const float* inp = (const float*)d_in[0];
    const float* tgt = (const float*)d_in[1];
    float* out = (float*)d_out;
    float* acc = (float*)d_ws;
    unsigned int* cnt = (unsigned int*)((char*)d_ws + 64);
    unsigned short* tmp = (unsigned short*)((char*)d_ws + 4096);  // 25.2 MB bf16 temp

    luv_hpass3<<<NIMG * 128, 256, 0, stream>>>(inp, tgt, tmp, acc, cnt);
    vpass4<<<NBLK_V, 64, 0, stream>>>(tmp, acc, cnt, out);
}

// Round 6
// 148.537 us; speedup vs baseline: 1.0929x; 1.0929x over previous
//
#include <hip/hip_runtime.h>
#include <math.h>

#define IMG_W 512
#define IMG_H 512
#define NIMG 16
#define HWSZ (IMG_W * IMG_H)          // 262144
#define CHWSZ (3 * HWSZ)              // 786432
#define NORM (1.0 / 4194304.0)        // 1 / (N*H*W)
#define NBLK_V 768                    // vpass blocks (4 waves each)

__device__ __forceinline__ float f_lab(float t) {
    float c = exp2f(log2f(t) * (1.0f / 3.0f));   // cbrt; small-t branch selected away
    return (t > 0.008856f) ? c : fmaf(7.787f, t, 0.13793103448275862f);
}

__device__ __forceinline__ void rgb_to_luv(float r, float g, float b,
                                           float& l, float& u, float& v) {
    float x = 0.4124564f * r + 0.3575761f * g + 0.1804375f * b;
    float y = 0.2126729f * r + 0.7151522f * g + 0.0721750f * b;
    float z = 0.0193339f * r + 0.1191920f * g + 0.9503041f * b;
    x *= (1.0f / 0.95047f);
    z *= (1.0f / 1.08883f);
    float fx = f_lab(x), fy = f_lab(y), fz = f_lab(z);
    l = 116.0f * fy - 16.0f;
    u = 13.0f * l * (fx - fy);
    v = 13.0f * l * (fy - fz);
}

__device__ __forceinline__ unsigned short f2bf(float x) {   // RNE f32->bf16
    unsigned int u = __float_as_uint(x);
    u += 0x7fff + ((u >> 16) & 1);
    return (unsigned short)(u >> 16);
}

// 15-tap horizontal sliding window across a wave-owned 512-px row (8 px/lane);
// halo via lane shuffles, zero padding at row ends. (validated R3)
__device__ __forceinline__ void hslide(const float d[8], float o[8], int lane) {
    float L[7], R[7];
    #pragma unroll
    for (int j = 0; j < 7; ++j) {
        float l = __shfl_up(d[j + 1], 1, 64);
        L[j] = (lane == 0) ? 0.0f : l;
        float r = __shfl_down(d[j], 1, 64);
        R[j] = (lane == 63) ? 0.0f : r;
    }
    float s = 0.0f;
    #pragma unroll
    for (int j = 0; j < 7; ++j) s += L[j];
    #pragma unroll
    for (int j = 0; j < 8; ++j) s += d[j];
    o[0] = s;
    #pragma unroll
    for (int k = 1; k < 8; ++k) o[k] = o[k - 1] + R[k - 1] - L[k - 1];
}

__device__ __forceinline__ uint4 pack8(const float o[8]) {
    uint4 p;
    p.x = (unsigned)f2bf(o[0]) | ((unsigned)f2bf(o[1]) << 16);
    p.y = (unsigned)f2bf(o[2]) | ((unsigned)f2bf(o[3]) << 16);
    p.z = (unsigned)f2bf(o[4]) | ((unsigned)f2bf(o[5]) << 16);
    p.w = (unsigned)f2bf(o[6]) | ((unsigned)f2bf(o[7]) << 16);
    return p;
}

// Block = 4 waves = 4 rows; wave owns a full 512-px row (8 px/lane).
// ALL 12 float4 loads issued into distinct registers before any math (ILP).
__global__ __launch_bounds__(256) void luv_hpass5(
        const float* __restrict__ inp, const float* __restrict__ tgt,
        unsigned short* __restrict__ tmp, float* __restrict__ acc,
        unsigned int* __restrict__ cnt) {
    int blk = blockIdx.x;
    if (blk == 0 && threadIdx.x == 0) { acc[0] = 0.0f; cnt[0] = 0u; }
    int n = blk >> 7;                            // 128 row-quads per image
    int lane = threadIdx.x & 63;
    int h = ((blk & 127) << 2) | (threadIdx.x >> 6);
    int w0 = lane << 3;
    size_t base = (size_t)n * CHWSZ + (size_t)h * IMG_W + w0;

    // ---- 12 independent 16B loads, all in flight together ----
    float R1[8], G1[8], B1[8], R2[8], G2[8], B2[8];
    *(float4*)&R1[0] = *(const float4*)(inp + base);
    *(float4*)&R1[4] = *(const float4*)(inp + base + 4);
    *(float4*)&G1[0] = *(const float4*)(inp + base + HWSZ);
    *(float4*)&G1[4] = *(const float4*)(inp + base + HWSZ + 4);
    *(float4*)&B1[0] = *(const float4*)(inp + base + 2 * HWSZ);
    *(float4*)&B1[4] = *(const float4*)(inp + base + 2 * HWSZ + 4);
    *(float4*)&R2[0] = *(const float4*)(tgt + base);
    *(float4*)&R2[4] = *(const float4*)(tgt + base + 4);
    *(float4*)&G2[0] = *(const float4*)(tgt + base + HWSZ);
    *(float4*)&G2[4] = *(const float4*)(tgt + base + HWSZ + 4);
    *(float4*)&B2[0] = *(const float4*)(tgt + base + 2 * HWSZ);
    *(float4*)&B2[4] = *(const float4*)(tgt + base + 2 * HWSZ + 4);

    float dl[8], du[8], dv[8];
    #pragma unroll
    for (int j = 0; j < 8; ++j) {
        float l1, u1, v1, l2, u2, v2;
        rgb_to_luv(R1[j], G1[j], B1[j], l1, u1, v1);
        rgb_to_luv(R2[j], G2[j], B2[j], l2, u2, v2);
        dl[j] = l1 - l2; du[j] = u1 - u2; dv[j] = v1 - v2;
    }

    float o[8];
    hslide(dl, o, lane);
    *reinterpret_cast<uint4*>(tmp + base) = pack8(o);
    hslide(du, o, lane);
    *reinterpret_cast<uint4*>(tmp + base + HWSZ) = pack8(o);
    hslide(dv, o, lane);
    *reinterpret_cast<uint4*>(tmp + base + 2 * HWSZ) = pack8(o);
}

__device__ __forceinline__ void unpack8(uint4 v, float f[8]) {
    f[0] = __uint_as_float(v.x << 16);
    f[1] = __uint_as_float(v.x & 0xffff0000u);
    f[2] = __uint_as_float(v.y << 16);
    f[3] = __uint_as_float(v.y & 0xffff0000u);
    f[4] = __uint_as_float(v.z << 16);
    f[5] = __uint_as_float(v.z & 0xffff0000u);
    f[6] = __uint_as_float(v.w << 16);
    f[7] = __uint_as_float(v.w & 0xffff0000u);
}

// One wave handles one 8-row segment across the full 512-col width
// (8 bf16 cols/thread, uint4 loads). Prime 15 rows, then 8 outputs with
// 7 batched add/sub row pairs. GLO: seg 0 (sub rows < 0). GHI: seg 63.
template <bool GLO, bool GHI>
__device__ __forceinline__ float vseg8(const unsigned short* __restrict__ col,
                                       int h0) {
    const uint4 z = make_uint4(0u, 0u, 0u, 0u);
    float W[8] = {0.f, 0.f, 0.f, 0.f, 0.f, 0.f, 0.f, 0.f};
    #pragma unroll
    for (int j = 0; j < 15; ++j) {               // rows h0-7 .. h0+7
        int hh = h0 - 7 + j;
        if (GLO && hh < 0) continue;             // resolved at unroll time
        uint4 v = *(const uint4*)(col + (size_t)hh * IMG_W);
        float a[8];
        unpack8(v, a);
        #pragma unroll
        for (int c = 0; c < 8; ++c) W[c] += a[c];
    }
    uint4 va[7], vs[7];
    #pragma unroll
    for (int j = 0; j < 7; ++j) {                // batched, all in flight
        int ha = h0 + 8 + j, hs = h0 - 7 + j;
        va[j] = (GHI && ha >= IMG_H) ? z : *(const uint4*)(col + (size_t)ha * IMG_W);
        vs[j] = (GLO && hs < 0)      ? z : *(const uint4*)(col + (size_t)hs * IMG_W);
    }
    float acc = 0.f;
    #pragma unroll
    for (int j = 0; j < 8; ++j) {
        #pragma unroll
        for (int c = 0; c < 8; ++c) acc += W[c] * W[c];
        if (j < 7) {
            float a[8], s[8];
            unpack8(va[j], a);
            unpack8(vs[j], s);
            #pragma unroll
            for (int c = 0; c < 8; ++c) W[c] += a[c] - s[c];
        }
    }
    return acc;
}

// 4 waves/block; wave -> (nc, seg). Grid 768 = 48 nc x 64 segs / 4.
__global__ __launch_bounds__(256) void vpass5(
        const unsigned short* __restrict__ tmp, float* __restrict__ acc,
        unsigned int* __restrict__ cnt, float* __restrict__ out) {
    int t = (int)threadIdx.x;
    int wid = t >> 6, lane = t & 63;
    int g = (blockIdx.x << 2) | wid;             // 0..3071
    int nc = g >> 6;                             // 0..47
    int seg = g & 63;
    const unsigned short* col = tmp + (size_t)nc * HWSZ + (lane << 3);
    int h0 = seg << 3;

    float a;
    if (seg == 0)       a = vseg8<true,  false>(col, h0);
    else if (seg == 63) a = vseg8<false, true >(col, h0);
    else                a = vseg8<false, false>(col, h0);

    #pragma unroll
    for (int off = 32; off > 0; off >>= 1)
        a += __shfl_down(a, off, 64);

    __shared__ float red[4];
    if (lane == 0) red[wid] = a;
    __syncthreads();
    if (t == 0) {
        float s = red[0] + red[1] + red[2] + red[3];
        atomicAdd(acc, s);
        __threadfence();
        unsigned int ticket = atomicAdd(cnt, 1u);
        if (ticket == NBLK_V - 1) {
            __threadfence();
            float tot = atomicAdd(acc, 0.0f);    // all adds complete & visible
            out[0] = (float)((double)tot * NORM);
        }
    }
}

extern "C" void kernel_launch(void* const* d_in, const int* in_sizes, int n_in,
                              void* d_out, int out_size, void* d_ws, size_t ws_size,
                              hipStream_t stream) {
    const float* inp = (const float*)d_in[0];
    const float* tgt = (const float*)d_in[1];
    float* out = (float*)d_out;
    float* acc = (float*)d_ws;
    unsigned int* cnt = (unsigned int*)((char*)d_ws + 64);
    unsigned short* tmp = (unsigned short*)((char*)d_ws + 4096);  // 25.2 MB bf16 temp

    luv_hpass5<<<NIMG * 128, 256, 0, stream>>>(inp, tgt, tmp, acc, cnt);
    vpass5<<<NBLK_V, 256, 0, stream>>>(tmp, acc, cnt, out);
}

// Round 7
// 131.756 us; speedup vs baseline: 1.2321x; 1.1274x over previous
//
#include <hip/hip_runtime.h>
#include <math.h>

#define IMG_W 512
#define IMG_H 512
#define NIMG 16
#define HWSZ (IMG_W * IMG_H)          // 262144
#define CHWSZ (3 * HWSZ)              // 786432
#define NORM (1.0 / 4194304.0)        // 1 / (N*H*W)
#define NBLK_V 768                    // vpass blocks (4 waves each, 3072 waves)

__device__ __forceinline__ float f_lab(float t) {
    float c = exp2f(log2f(t) * (1.0f / 3.0f));   // cbrt; small-t branch selected away
    return (t > 0.008856f) ? c : fmaf(7.787f, t, 0.13793103448275862f);
}

__device__ __forceinline__ void rgb_to_luv(float r, float g, float b,
                                           float& l, float& u, float& v) {
    float x = 0.4124564f * r + 0.3575761f * g + 0.1804375f * b;
    float y = 0.2126729f * r + 0.7151522f * g + 0.0721750f * b;
    float z = 0.0193339f * r + 0.1191920f * g + 0.9503041f * b;
    x *= (1.0f / 0.95047f);
    z *= (1.0f / 1.08883f);
    float fx = f_lab(x), fy = f_lab(y), fz = f_lab(z);
    l = 116.0f * fy - 16.0f;
    u = 13.0f * l * (fx - fy);
    v = 13.0f * l * (fy - fz);
}

__device__ __forceinline__ unsigned short f2bf(float x) {   // RNE f32->bf16
    unsigned int u = __float_as_uint(x);
    u += 0x7fff + ((u >> 16) & 1);
    return (unsigned short)(u >> 16);
}

// 15-tap horizontal sliding window across a wave-owned 512-px row (8 px/lane);
// halo via lane shuffles, zero padding at row ends. (validated R3)
__device__ __forceinline__ void hslide(const float d[8], float o[8], int lane) {
    float L[7], R[7];
    #pragma unroll
    for (int j = 0; j < 7; ++j) {
        float l = __shfl_up(d[j + 1], 1, 64);
        L[j] = (lane == 0) ? 0.0f : l;
        float r = __shfl_down(d[j], 1, 64);
        R[j] = (lane == 63) ? 0.0f : r;
    }
    float s = 0.0f;
    #pragma unroll
    for (int j = 0; j < 7; ++j) s += L[j];
    #pragma unroll
    for (int j = 0; j < 8; ++j) s += d[j];
    o[0] = s;
    #pragma unroll
    for (int k = 1; k < 8; ++k) o[k] = o[k - 1] + R[k - 1] - L[k - 1];
}

__device__ __forceinline__ uint4 pack8(const float o[8]) {
    uint4 p;
    p.x = (unsigned)f2bf(o[0]) | ((unsigned)f2bf(o[1]) << 16);
    p.y = (unsigned)f2bf(o[2]) | ((unsigned)f2bf(o[3]) << 16);
    p.z = (unsigned)f2bf(o[4]) | ((unsigned)f2bf(o[5]) << 16);
    p.w = (unsigned)f2bf(o[6]) | ((unsigned)f2bf(o[7]) << 16);
    return p;
}

// Block = 4 waves = 4 rows; wave owns a full 512-px row (8 px/lane).
// ALL 12 float4 loads issued into distinct registers before any math (ILP).
// No LDS, no barriers, no atomics.
__global__ __launch_bounds__(256) void luv_hpass5(
        const float* __restrict__ inp, const float* __restrict__ tgt,
        unsigned short* __restrict__ tmp) {
    int blk = blockIdx.x;
    int n = blk >> 7;                            // 128 row-quads per image
    int lane = threadIdx.x & 63;
    int h = ((blk & 127) << 2) | (threadIdx.x >> 6);
    int w0 = lane << 3;
    size_t base = (size_t)n * CHWSZ + (size_t)h * IMG_W + w0;

    // ---- 12 independent 16B loads, all in flight together ----
    float R1[8], G1[8], B1[8], R2[8], G2[8], B2[8];
    *(float4*)&R1[0] = *(const float4*)(inp + base);
    *(float4*)&R1[4] = *(const float4*)(inp + base + 4);
    *(float4*)&G1[0] = *(const float4*)(inp + base + HWSZ);
    *(float4*)&G1[4] = *(const float4*)(inp + base + HWSZ + 4);
    *(float4*)&B1[0] = *(const float4*)(inp + base + 2 * HWSZ);
    *(float4*)&B1[4] = *(const float4*)(inp + base + 2 * HWSZ + 4);
    *(float4*)&R2[0] = *(const float4*)(tgt + base);
    *(float4*)&R2[4] = *(const float4*)(tgt + base + 4);
    *(float4*)&G2[0] = *(const float4*)(tgt + base + HWSZ);
    *(float4*)&G2[4] = *(const float4*)(tgt + base + HWSZ + 4);
    *(float4*)&B2[0] = *(const float4*)(tgt + base + 2 * HWSZ);
    *(float4*)&B2[4] = *(const float4*)(tgt + base + 2 * HWSZ + 4);

    float dl[8], du[8], dv[8];
    #pragma unroll
    for (int j = 0; j < 8; ++j) {
        float l1, u1, v1, l2, u2, v2;
        rgb_to_luv(R1[j], G1[j], B1[j], l1, u1, v1);
        rgb_to_luv(R2[j], G2[j], B2[j], l2, u2, v2);
        dl[j] = l1 - l2; du[j] = u1 - u2; dv[j] = v1 - v2;
    }

    float o[8];
    hslide(dl, o, lane);
    *reinterpret_cast<uint4*>(tmp + base) = pack8(o);
    hslide(du, o, lane);
    *reinterpret_cast<uint4*>(tmp + base + HWSZ) = pack8(o);
    hslide(dv, o, lane);
    *reinterpret_cast<uint4*>(tmp + base + 2 * HWSZ) = pack8(o);
}

__device__ __forceinline__ void unpack8(uint4 v, float f[8]) {
    f[0] = __uint_as_float(v.x << 16);
    f[1] = __uint_as_float(v.x & 0xffff0000u);
    f[2] = __uint_as_float(v.y << 16);
    f[3] = __uint_as_float(v.y & 0xffff0000u);
    f[4] = __uint_as_float(v.z << 16);
    f[5] = __uint_as_float(v.z & 0xffff0000u);
    f[6] = __uint_as_float(v.w << 16);
    f[7] = __uint_as_float(v.w & 0xffff0000u);
}

// One wave handles one 8-row segment across the full 512-col width
// (8 bf16 cols/thread, uint4 loads). Prime 15 rows, then 8 outputs with
// 7 batched add/sub row pairs. (validated R6, absmax 0)
template <bool GLO, bool GHI>
__device__ __forceinline__ float vseg8(const unsigned short* __restrict__ col,
                                       int h0) {
    const uint4 z = make_uint4(0u, 0u, 0u, 0u);
    float W[8] = {0.f, 0.f, 0.f, 0.f, 0.f, 0.f, 0.f, 0.f};
    #pragma unroll
    for (int j = 0; j < 15; ++j) {               // rows h0-7 .. h0+7
        int hh = h0 - 7 + j;
        if (GLO && hh < 0) continue;             // resolved at unroll time
        uint4 v = *(const uint4*)(col + (size_t)hh * IMG_W);
        float a[8];
        unpack8(v, a);
        #pragma unroll
        for (int c = 0; c < 8; ++c) W[c] += a[c];
    }
    uint4 va[7], vs[7];
    #pragma unroll
    for (int j = 0; j < 7; ++j) {                // batched, all in flight
        int ha = h0 + 8 + j, hs = h0 - 7 + j;
        va[j] = (GHI && ha >= IMG_H) ? z : *(const uint4*)(col + (size_t)ha * IMG_W);
        vs[j] = (GLO && hs < 0)      ? z : *(const uint4*)(col + (size_t)hs * IMG_W);
    }
    float acc = 0.f;
    #pragma unroll
    for (int j = 0; j < 8; ++j) {
        #pragma unroll
        for (int c = 0; c < 8; ++c) acc += W[c] * W[c];
        if (j < 7) {
            float a[8], s[8];
            unpack8(va[j], a);
            unpack8(vs[j], s);
            #pragma unroll
            for (int c = 0; c < 8; ++c) W[c] += a[c] - s[c];
        }
    }
    return acc;
}

// 4 waves/block; wave -> (nc, seg). Grid 768 = 48 nc x 64 segs / 4.
// NO atomics: per-block partial write only.
__global__ __launch_bounds__(256) void vpass6(
        const unsigned short* __restrict__ tmp, float* __restrict__ partial) {
    int t = (int)threadIdx.x;
    int wid = t >> 6, lane = t & 63;
    int g = ((int)blockIdx.x << 2) | wid;        // 0..3071
    int nc = g >> 6;                             // 0..47
    int seg = g & 63;
    const unsigned short* col = tmp + (size_t)nc * HWSZ + (lane << 3);
    int h0 = seg << 3;

    float a;
    if (seg == 0)       a = vseg8<true,  false>(col, h0);
    else if (seg == 63) a = vseg8<false, true >(col, h0);
    else                a = vseg8<false, false>(col, h0);

    #pragma unroll
    for (int off = 32; off > 0; off >>= 1)
        a += __shfl_down(a, off, 64);

    __shared__ float red[4];
    if (lane == 0) red[wid] = a;
    __syncthreads();
    if (t == 0)
        partial[blockIdx.x] = red[0] + red[1] + red[2] + red[3];
}

__global__ __launch_bounds__(256) void finalize3(
        const float* __restrict__ partial, float* __restrict__ out) {
    int t = (int)threadIdx.x;
    float a = 0.0f;
    #pragma unroll
    for (int i = 0; i < NBLK_V; i += 256) a += partial[i + t];
    #pragma unroll
    for (int off = 32; off > 0; off >>= 1)
        a += __shfl_down(a, off, 64);
    __shared__ float red[4];
    int lane = t & 63, wid = t >> 6;
    if (lane == 0) red[wid] = a;
    __syncthreads();
    if (t == 0)
        out[0] = (float)((double)(red[0] + red[1] + red[2] + red[3]) * NORM);
}

extern "C" void kernel_launch(void* const* d_in, const int* in_sizes, int n_in,
                              void* d_out, int out_size, void* d_ws, size_t ws_size,
                              hipStream_t stream) {
    const float* inp = (const float*)d_in[0];
    const float* tgt = (const float*)d_in[1];
    float* out = (float*)d_out;
    float* partial = (float*)d_ws;                                // 768 floats
    unsigned short* tmp = (unsigned short*)((char*)d_ws + 4096);  // 25.2 MB bf16 temp

    luv_hpass5<<<NIMG * 128, 256, 0, stream>>>(inp, tgt, tmp);
    vpass6<<<NBLK_V, 256, 0, stream>>>(tmp, partial);
    finalize3<<<1, 256, 0, stream>>>(partial, out);
}